// Round 1
// baseline (1082.419 us; speedup 1.0000x reference)
//
#include <hip/hip_runtime.h>
#include <stdint.h>

// ---------------------------------------------------------------------------
// QuantumQLSTM fused: T=2048, B=512, D=128, H=128, NQ=8.  FP32 in/out.
// One kernel, 256 blocks x 64 threads (1 wave/block, ~1 wave/CU).
// Each wave owns 2 batch rows. Latency-bound on the 2048-step serial chain,
// so this revision shortens the chain:
//   * lane remap: gate = lane&3, wirepair = (lane>>2)&3; each lane sums
//     wires q and q+4 (lanes 16-31 duplicate 0-15). 8-wire reduce is
//     add + row_ror:4 + row_ror:8 (in-row DPP only), and the 4 gate
//     scalars land inside every quad -> gather via 4 parallel quad_perm
//     DPP movs. This removes the 4x ds_bpermute + lgkmcnt(0) (~120 cy)
//     from every serial step.
//   * GEMM staging (splitv + MFMA pieces) interleaved INTO the 8-step
//     chain loop so its issue cycles hide in the chain's stall bubbles.
//   * algebra folds: carry cc = 2*log2e*c; gather raw sigmoids and fold
//     the tanh-gate transform into the i*g product; fold h = og*tanh(c)
//     into r_next = fma(-2*og*wrev, rc, og*wrev + zx).
// Recurrence math identical to the validated R2 version (absmax ~9.8e-4):
//   qgate = 0.5 - sum_q cos(2pi*(zx_q + h*wsum_q/2pi))/16.
// ---------------------------------------------------------------------------

typedef __attribute__((ext_vector_type(8))) short short8;
typedef __attribute__((ext_vector_type(4))) float float4v;

#define TSTEPS 2048
#define BATCH  512
#define DIMX   128
#define HID    128
#define TBLK   (TSTEPS / 8)      // 256 t-blocks
#define LROW   33                // LDS row pitch (pad +1: conflict-free)
#define LBUF   (16 * LROW)       // 528 floats per buffer

template <int CTRL>
__device__ __forceinline__ float dppf(float x) {
  return __int_as_float(
      __builtin_amdgcn_mov_dpp(__float_as_int(x), CTRL, 0xF, 0xF, true));
}

// split 8 fp32 into truncated-hi + truncated-lo bf16 (err ~2^-16 relative)
__device__ __forceinline__ void splitv(float4v a, float4v b,
                                       short8& hi, short8& lo) {
#pragma unroll
  for (int j = 0; j < 8; ++j) {
    float x = (j < 4) ? a[j] : b[j - 4];
    unsigned int u = __float_as_uint(x);
    float r = x - __uint_as_float(u & 0xFFFF0000u);   // exact fp32 residual
    hi[j] = (short)(u >> 16);
    lo[j] = (short)(__float_as_uint(r) >> 16);
  }
}

__global__ __launch_bounds__(64) void qlstm_fused(
    const float* __restrict__ X,
    const float* __restrict__ Wf, const float* __restrict__ bfv,
    const float* __restrict__ Wi, const float* __restrict__ biv,
    const float* __restrict__ Wu, const float* __restrict__ buv,
    const float* __restrict__ Wo, const float* __restrict__ bov,
    float* __restrict__ out)
{
  __shared__ float Zl[2 * LBUF];

  const int lane  = threadIdx.x;        // 0..63
  const int m     = lane & 15;          // MFMA: A-row / C-col index
  const int quad  = lane >> 4;
  const int g32   = lane & 31;
  const int gate  = g32 & 3;            // chain: gate in low 2 bits (quad!)
  const int qq    = (g32 >> 2) & 3;     // wire pair: handles qq and qq+4
  const int bhalf = lane >> 5;
  const int b0    = blockIdx.x * 2;

  // ---- B fragments (weights, hi/lo split), biases -------------------------
  const int qm = m & 7;
  const float* Bt0 = (m < 8) ? Wf : Wi;     // C cols 0..15 -> f,i
  const float* Bt1 = (m < 8) ? Wu : Wo;     // C cols 16..31 -> u,o
  short8 b0h[4], b0l[4], b1h[4], b1l[4];
#pragma unroll
  for (int ks = 0; ks < 4; ++ks) {
    const float* p0 = Bt0 + qm * 256 + ks * 32 + quad * 8;
    const float* p1 = Bt1 + qm * 256 + ks * 32 + quad * 8;
    splitv(*(const float4v*)p0, *(const float4v*)(p0 + 4), b0h[ks], b0l[ks]);
    splitv(*(const float4v*)p1, *(const float4v*)(p1 + 4), b1h[ks], b1l[ks]);
  }
  const float INV2PI = 0.15915494309189535f;
  const float bias0 = ((m < 8) ? bfv : biv)[qm];
  const float bias1 = ((m < 8) ? buv : bov)[qm];

  // ---- chain constants: this lane covers wires qq and qq+4 of `gate` ------
  const float* Wsel = (gate == 0) ? Wf : (gate == 1) ? Wi
                    : (gate == 2) ? Wu : Wo;
  const float* wpa = Wsel + qq * 256 + 128;
  const float* wpb = Wsel + (qq + 4) * 256 + 128;
  float wsa = 0.f, wsb = 0.f;
#pragma unroll 8
  for (int j = 0; j < 128; ++j) { wsa += wpa[j]; wsb += wpb[j]; }
  const float wrev0 = wsa * INV2PI;
  const float wrev1 = wsb * INV2PI;

  const float L2E = 1.4426950408889634f;
  const float ka = (gate == 2) ? (L2E / 8.f) : (L2E / 16.f);
  const float kb = (gate == 2) ? (-L2E)      : (-0.5f * L2E);
  const int zc0 = gate * 8 + qq;       // z column of wire qq
  const int zc1 = zc0 + 4;             // z column of wire qq+4

  // ---- A-fragment base: row m -> (t_local = m>>1, b = b0 + (m&1)) ---------
  const float* arow = X + ((long)(m >> 1) * BATCH + b0 + (m & 1)) * DIMX;
  float4v Aa[8];

#define LOADA(tb)                                                            \
  {                                                                          \
    const float* p_ = arow + (long)(tb) * (8 * BATCH * DIMX);                \
    _Pragma("unroll")                                                        \
    for (int ks_ = 0; ks_ < 4; ++ks_) {                                      \
      Aa[2 * ks_]     = *(const float4v*)(p_ + ks_ * 32 + quad * 8);         \
      Aa[2 * ks_ + 1] = *(const float4v*)(p_ + ks_ * 32 + quad * 8 + 4);     \
    }                                                                        \
  }

// full produce (prologue only; steady state is interleaved into the loop)
#define PRODUCE(buf)                                                         \
  {                                                                          \
    float4v acc0 = {0.f, 0.f, 0.f, 0.f};                                     \
    float4v acc1 = {0.f, 0.f, 0.f, 0.f};                                     \
    _Pragma("unroll")                                                        \
    for (int ks_ = 0; ks_ < 4; ++ks_) {                                      \
      short8 ah_, al_;                                                       \
      splitv(Aa[2 * ks_], Aa[2 * ks_ + 1], ah_, al_);                        \
      acc0 = __builtin_amdgcn_mfma_f32_16x16x32_bf16(ah_, b0h[ks_], acc0, 0, 0, 0); \
      acc0 = __builtin_amdgcn_mfma_f32_16x16x32_bf16(al_, b0h[ks_], acc0, 0, 0, 0); \
      acc0 = __builtin_amdgcn_mfma_f32_16x16x32_bf16(ah_, b0l[ks_], acc0, 0, 0, 0); \
      acc1 = __builtin_amdgcn_mfma_f32_16x16x32_bf16(ah_, b1h[ks_], acc1, 0, 0, 0); \
      acc1 = __builtin_amdgcn_mfma_f32_16x16x32_bf16(al_, b1h[ks_], acc1, 0, 0, 0); \
      acc1 = __builtin_amdgcn_mfma_f32_16x16x32_bf16(ah_, b1l[ks_], acc1, 0, 0, 0); \
    }                                                                        \
    _Pragma("unroll")                                                        \
    for (int r_ = 0; r_ < 4; ++r_) {                                         \
      int row_ = quad * 4 + r_;                                              \
      Zl[(buf) * LBUF + row_ * LROW + m]      = (acc0[r_] + bias0) * INV2PI; \
      Zl[(buf) * LBUF + row_ * LROW + m + 16] = (acc1[r_] + bias1) * INV2PI; \
    }                                                                        \
  }

  // chain state (uniform across each 32-lane half except ogw*/n2g*)
  float cc = 0.f;                       // 2*log2(e) * c
  float rc = 0.f;                       // 1/(1+exp2(cc)) from prev step
  float og = 0.f;
  float ogw0 = 0.f, ogw1 = 0.f;         // og*wrev for this lane's 2 wires
  float n2g0 = 0.f, n2g1 = 0.f;         // -2*ogw
  float h = 0.f;
  float* orow = out + (long)(b0 + bhalf) * HID + g32 * 4;

  // prologue: fill buf0 with t-block 0, then prefetch t-block 1
  LOADA(0);
  PRODUCE(0);
  LOADA(1);

  for (int k = 0; k < TBLK; ++k) {
    const int wbuf = (k + 1) & 1;

    // hoist this t-block's z values into registers (no DS on the chain)
    const float* zb = Zl + (k & 1) * LBUF + bhalf * LROW;
    float zx0[8], zx1[8];
#pragma unroll
    for (int j = 0; j < 8; ++j) {
      zx0[j] = zb[j * 2 * LROW + zc0];
      zx1[j] = zb[j * 2 * LROW + zc1];
    }

    float4v acc0 = {0.f, 0.f, 0.f, 0.f};
    float4v acc1 = {0.f, 0.f, 0.f, 0.f};
    short8 ah, al;

#pragma unroll
    for (int j = 0; j < 8; ++j) {
      // ---- interleaved GEMM piece for t-block k+1 (hides in chain stalls)
      {
        const int ks = j >> 1;
        if ((j & 1) == 0) {
          splitv(Aa[2 * ks], Aa[2 * ks + 1], ah, al);
          acc0 = __builtin_amdgcn_mfma_f32_16x16x32_bf16(ah, b0h[ks], acc0, 0, 0, 0);
          acc0 = __builtin_amdgcn_mfma_f32_16x16x32_bf16(al, b0h[ks], acc0, 0, 0, 0);
          acc0 = __builtin_amdgcn_mfma_f32_16x16x32_bf16(ah, b0l[ks], acc0, 0, 0, 0);
        } else {
          acc1 = __builtin_amdgcn_mfma_f32_16x16x32_bf16(ah, b1h[ks], acc1, 0, 0, 0);
          acc1 = __builtin_amdgcn_mfma_f32_16x16x32_bf16(al, b1h[ks], acc1, 0, 0, 0);
          acc1 = __builtin_amdgcn_mfma_f32_16x16x32_bf16(ah, b1l[ks], acc1, 0, 0, 0);
        }
        if (j == 7) {
#pragma unroll
          for (int r_ = 0; r_ < 4; ++r_) {
            int row_ = quad * 4 + r_;
            Zl[wbuf * LBUF + row_ * LROW + m]      = (acc0[r_] + bias0) * INV2PI;
            Zl[wbuf * LBUF + row_ * LROW + m + 16] = (acc1[r_] + bias1) * INV2PI;
          }
          int kn = k + 2; if (kn > TBLK - 1) kn = TBLK - 1;
          LOADA(kn);                    // prefetch t-block k+2
        }
      }

      // ---- serial chain step (t = 8k + j) -------------------------------
      // r = h*wrev + zx, folded: (ogw + zx) - 2*ogw*rc
      float r0 = __builtin_fmaf(n2g0, rc, ogw0 + zx0[j]);
      float r1 = __builtin_fmaf(n2g1, rc, ogw1 + zx1[j]);
      float cs = __builtin_amdgcn_cosf(r0) + __builtin_amdgcn_cosf(r1);

      float s1 = cs + dppf<0x124>(cs);  // row_ror:4  (pairs within row)
      float s  = s1 + dppf<0x128>(s1);  // row_ror:8  -> full 8-wire sum

      float e  = __builtin_amdgcn_exp2f(__builtin_fmaf(s, ka, kb));
      float v  = __builtin_amdgcn_rcpf(1.f + e);   // raw sigmoid, all gates

      float fg = dppf<0x00>(v);         // quad_perm(0,0,0,0) -> f
      float ig = dppf<0x55>(v);         // -> i
      float ug = dppf<0xAA>(v);         // -> sigma_u (raw)
      og       = dppf<0xFF>(v);         // -> o

      // cc += : 2*L2E*i*(2*sigma_u - 1) = (4*L2E*sigma_u)*i - 2*L2E*i
      float igug2 = __builtin_fmaf(ug * (4.f * L2E), ig, ig * (-2.f * L2E));
      cc = __builtin_fmaf(fg, cc, igug2);

      float e2 = __builtin_amdgcn_exp2f(cc);       // e^(2c)
      rc = __builtin_amdgcn_rcpf(1.f + e2);

      h = __builtin_fmaf(-2.f * og, rc, og);       // og * tanh(c)
      ogw0 = og * wrev0;  n2g0 = -2.f * ogw0;      // off-chain, for next r
      ogw1 = og * wrev1;  n2g1 = -2.f * ogw1;

      float4v hv = {h, h, h, h};
      *(float4v*)orow = hv;
      orow += (long)BATCH * HID;
    }
  }

  // finals: hx then cx, each [B, H]
  const float HALF_LN2 = 0.34657359027997264f;     // cc -> c
  float cfin = cc * HALF_LN2;
  float4v hv = {h, h, h, h};
  float4v cv = {cfin, cfin, cfin, cfin};
  float* hxp = out + (long)TSTEPS * BATCH * HID + (long)(b0 + bhalf) * HID + g32 * 4;
  *(float4v*)hxp = hv;
  *(float4v*)(hxp + BATCH * HID) = cv;
#undef LOADA
#undef PRODUCE
}

// ---------------------------------------------------------------------------
extern "C" void kernel_launch(void* const* d_in, const int* in_sizes, int n_in,
                              void* d_out, int out_size, void* d_ws, size_t ws_size,
                              hipStream_t stream) {
  (void)in_sizes; (void)n_in; (void)out_size; (void)d_ws; (void)ws_size;
  const float* X   = (const float*)d_in[0];
  const float* Wf  = (const float*)d_in[1];
  const float* bfv = (const float*)d_in[2];
  const float* Wi  = (const float*)d_in[3];
  const float* biv = (const float*)d_in[4];
  const float* Wu  = (const float*)d_in[5];
  const float* buv = (const float*)d_in[6];
  const float* Wo  = (const float*)d_in[7];
  const float* bov = (const float*)d_in[8];
  float* out = (float*)d_out;

  qlstm_fused<<<BATCH / 2, 64, 0, stream>>>(X, Wf, bfv, Wi, biv, Wu, buv, Wo, bov, out);
}